// Round 5
// baseline (12930.280 us; speedup 1.0000x reference)
//
#include <hip/hip_runtime.h>
#include <cfloat>
#include <cstdint>

#define N_PTS 16384
#define KNN_K 16
#define KNN_TILE 512
#define CERT_EPS 3e-6f

// ---------------------------------------------------------------------------
// KNN: one wave per query point, per-lane top-16 (fp64 exact) + wave merge.
// ---------------------------------------------------------------------------
__global__ __launch_bounds__(256) void knn_kernel(const float* __restrict__ pts,
                                                  int* __restrict__ knn_out) {
    __shared__ float sx[KNN_TILE], sy[KNN_TILE], sz[KNN_TILE];
    const int wave = threadIdx.x >> 6;
    const int lane = threadIdx.x & 63;
    const int qi = blockIdx.x * 4 + wave;
    const double qxd = (double)pts[qi * 3 + 0];
    const double qyd = (double)pts[qi * 3 + 1];
    const double qzd = (double)pts[qi * 3 + 2];

    double ld[16];
    int li[16];
#pragma unroll
    for (int s = 0; s < 16; ++s) { ld[s] = DBL_MAX; li[s] = 0x7fffffff; }
    double md = DBL_MAX; int mj = 0x7fffffff; int mslot = 0;

    for (int t0 = 0; t0 < N_PTS; t0 += KNN_TILE) {
        __syncthreads();
        for (int t = threadIdx.x; t < KNN_TILE; t += 256) {
            sx[t] = pts[(t0 + t) * 3 + 0];
            sy[t] = pts[(t0 + t) * 3 + 1];
            sz[t] = pts[(t0 + t) * 3 + 2];
        }
        __syncthreads();
#pragma unroll
        for (int m = 0; m < KNN_TILE / 64; ++m) {
            const int c = lane + m * 64;
            const int j = t0 + c;
            if (j == qi) continue;  // diagonal excluded (d=inf in reference)
            double dx = qxd - (double)sx[c];
            double dy = qyd - (double)sy[c];
            double dz = qzd - (double)sz[c];
            double dd = dx * dx + dy * dy + dz * dz;
            if (dd < md || (dd == md && j < mj)) {
#pragma unroll
                for (int s = 0; s < 16; ++s)
                    if (s == mslot) { ld[s] = dd; li[s] = j; }
                md = -1.0; mj = -1; mslot = 0;
#pragma unroll
                for (int s = 0; s < 16; ++s) {
                    bool g = (ld[s] > md) || (ld[s] == md && li[s] > mj);
                    if (g) { md = ld[s]; mj = li[s]; mslot = s; }
                }
            }
        }
    }

    const int out_base = qi * KNN_K;
    for (int r = 0; r < KNN_K; ++r) {
        double cd = DBL_MAX; int cj = 0x7fffffff; int cs = 0;
#pragma unroll
        for (int s = 0; s < 16; ++s) {
            bool l = (ld[s] < cd) || (ld[s] == cd && li[s] < cj);
            if (l) { cd = ld[s]; cj = li[s]; cs = s; }
        }
        double wd = cd; int wj = cj;
        for (int off = 32; off; off >>= 1) {
            double od = __shfl_xor(wd, off);
            int oj = __shfl_xor(wj, off);
            if (od < wd || (od == wd && oj < wj)) { wd = od; wj = oj; }
        }
        if (cd == wd && cj == wj) {
#pragma unroll
            for (int s = 0; s < 16; ++s)
                if (s == cs) { ld[s] = DBL_MAX; li[s] = 0x7fffffff; }
        }
        if (lane == 0) knn_out[out_base + r] = wj;
    }
}

// ---------------------------------------------------------------------------
// EdgeConv MLP + maxpool: one wave per point (lane = channel 0..63).
// ---------------------------------------------------------------------------
__global__ __launch_bounds__(256) void edgeconv_kernel(
    const float* __restrict__ pts, const int* __restrict__ knn,
    const float* __restrict__ ew1, const float* __restrict__ eb1,
    const float* __restrict__ ew2, const float* __restrict__ eb2,
    float* __restrict__ feats) {
    __shared__ float w1[6 * 64], b1v[64], w2[64 * 64], b2v[64];
    for (int t = threadIdx.x; t < 6 * 64; t += 256) w1[t] = ew1[t];
    for (int t = threadIdx.x; t < 64; t += 256) { b1v[t] = eb1[t]; b2v[t] = eb2[t]; }
    for (int t = threadIdx.x; t < 64 * 64; t += 256) w2[t] = ew2[t];
    __syncthreads();

    const int wave = threadIdx.x >> 6, lane = threadIdx.x & 63;
    const int p = blockIdx.x * 4 + wave;
    const float xi = pts[p * 3], yi = pts[p * 3 + 1], zi = pts[p * 3 + 2];
    float acc = -FLT_MAX;
    for (int k = 0; k < KNN_K; ++k) {
        const int j = knn[p * 16 + k];
        const float xj = pts[j * 3], yj = pts[j * 3 + 1], zj = pts[j * 3 + 2];
        const float f0 = xi, f1 = yi, f2 = zi;
        const float f3 = xj - xi, f4 = yj - yi, f5 = zj - zi;
        float h1 = b1v[lane];
        h1 = fmaf(f0, w1[0 * 64 + lane], h1);
        h1 = fmaf(f1, w1[1 * 64 + lane], h1);
        h1 = fmaf(f2, w1[2 * 64 + lane], h1);
        h1 = fmaf(f3, w1[3 * 64 + lane], h1);
        h1 = fmaf(f4, w1[4 * 64 + lane], h1);
        h1 = fmaf(f5, w1[5 * 64 + lane], h1);
        h1 = fmaxf(h1, 0.0f);
        float h2 = b2v[lane];
        for (int d = 0; d < 64; ++d)
            h2 = fmaf(__shfl(h1, d), w2[d * 64 + lane], h2);
        acc = fmaxf(acc, h2);
    }
    feats[p * 64 + lane] = acc;
}

// ---------------------------------------------------------------------------
// FPS v5: T=512 threads, P = n/512 pts/thread. x,y live in LDS (float2,
// ds_read_b64, stride-1 per lane => conflict-free); z and c stay in registers
// (2*P + ~45 regs ~= 110 < 128 cap => allocator cannot spill — R3/R4's 116-VGPR
// scratch thrash is structurally eliminated). Hot-loop numerics bitwise-
// identical to the validated R3/R4 path: certified fp32 + per-thread top-2 +
// wave butterfly + 1 barrier + 8-slot merge; cooperative fp64 fallback when
// the global top-2 gap < CERT_EPS rel (rare).
// ---------------------------------------------------------------------------
template <int T, int P>
__global__ __launch_bounds__(T) void fps_kernel(const float* __restrict__ pts,
                                                int n_out,
                                                int* __restrict__ fi) {
    constexpr int NW = T / 64;
    constexpr int N = T * P;
    __shared__ float2 sxy[N];                 // 8 B * N  (128 KiB at N=16384)
    __shared__ float rm1[2][NW];
    __shared__ int rg1[2][NW];
    __shared__ float rm2[2][NW];
    __shared__ int cand_idx[64];
    __shared__ int cand_cnt;
    __shared__ int more_flag;
    __shared__ double red_d[NW];
    const int tid = threadIdx.x;
    const int wave = tid >> 6, lane = tid & 63;

    float zr[P], c[P];
#pragma unroll
    for (int q = 0; q < P; ++q) {
        const int g = tid + q * T;
        float x = pts[g * 3 + 0];
        float y = pts[g * 3 + 1];
        zr[q] = pts[g * 3 + 2];
        sxy[g] = make_float2(x, y);
        c[q] = FLT_MAX;
    }
    float sx = pts[0], sy = pts[1], sz = pts[2];
    if (tid == 0) fi[0] = 0;
    __syncthreads();

    for (int it = 1; it < n_out; ++it) {
        // fused min-update + per-thread top-2 (xy from LDS, z/c in registers)
        float m1 = -1.0f, m2 = -1.0f;
        int g1 = 0x7fffffff;
#pragma unroll
        for (int q = 0; q < P; ++q) {
            float2 xy = sxy[tid + q * T];
            float dx = xy.x - sx, dy = xy.y - sy, dz = zr[q] - sz;
            float t = fmaf(dx, dx, fmaf(dy, dy, dz * dz));
            float nc = fminf(c[q], t);
            c[q] = nc;
            bool gt = nc > m1;
            m2 = fmaxf(m2, fminf(nc, m1));
            m1 = fmaxf(m1, nc);
            g1 = gt ? (tid + q * T) : g1;
        }
        // wave butterfly top-2 merge
        for (int off = 32; off; off >>= 1) {
            float om1 = __shfl_xor(m1, off);
            int og1 = __shfl_xor(g1, off);
            float om2 = __shfl_xor(m2, off);
            bool take = (om1 > m1) || (om1 == m1 && og1 < g1);
            float sml = take ? m1 : om1;
            m2 = fmaxf(fmaxf(m2, om2), sml);
            m1 = take ? om1 : m1;
            g1 = take ? og1 : g1;
        }
        const int par = it & 1;
        if (lane == 0) { rm1[par][wave] = m1; rg1[par][wave] = g1; rm2[par][wave] = m2; }
        __syncthreads();
        float M1 = rm1[par][0], M2 = rm2[par][0];
        int G1 = rg1[par][0];
#pragma unroll
        for (int w = 1; w < NW; ++w) {
            float om1 = rm1[par][w], om2 = rm2[par][w];
            int og1 = rg1[par][w];
            bool take = (om1 > M1) || (om1 == M1 && og1 < G1);
            float sml = take ? M1 : om1;
            M2 = fmaxf(fmaxf(M2, om2), sml);
            M1 = take ? om1 : M1;
            G1 = take ? og1 : G1;
        }
        int winner = G1;
        const float thr = M1 - M1 * CERT_EPS;
        if (M2 >= thr) {
            // ---- cooperative exact fp64 fallback (uniform branch) ----
            unsigned miss = 0;
#pragma unroll
            for (int q = 0; q < P; ++q)
                if (c[q] >= thr) miss |= (1u << q);
            double BD = -1.0;
            int BG = 0x7fffffff;
            for (;;) {
                if (tid == 0) { cand_cnt = 0; more_flag = 0; }
                __syncthreads();
#pragma unroll
                for (int q = 0; q < P; ++q) {
                    if (miss & (1u << q)) {
                        int slot = atomicAdd(&cand_cnt, 1);
                        if (slot < 64) {
                            cand_idx[slot] = tid + q * T;
                            miss &= ~(1u << q);
                        } else {
                            more_flag = 1;
                        }
                    }
                }
                __syncthreads();
                int ncand = cand_cnt;
                if (ncand > 64) ncand = 64;
                for (int ci = 0; ci < ncand; ++ci) {
                    const int g = cand_idx[ci];
                    const double qx = (double)pts[g * 3 + 0];
                    const double qy = (double)pts[g * 3 + 1];
                    const double qz = (double)pts[g * 3 + 2];
                    double dmin = DBL_MAX;
                    for (int i = tid; i < it; i += T) {
                        const int h = fi[i];
                        double ddx = qx - (double)pts[h * 3 + 0];
                        double ddy = qy - (double)pts[h * 3 + 1];
                        double ddz = qz - (double)pts[h * 3 + 2];
                        double dd = ddx * ddx + ddy * ddy + ddz * ddz;
                        dmin = (dd < dmin) ? dd : dmin;
                    }
                    for (int off = 32; off; off >>= 1) {
                        double od = __shfl_xor(dmin, off);
                        dmin = (od < dmin) ? od : dmin;
                    }
                    if (lane == 0) red_d[wave] = dmin;
                    __syncthreads();
                    double dall = red_d[0];
#pragma unroll
                    for (int w = 1; w < NW; ++w) dall = (red_d[w] < dall) ? red_d[w] : dall;
                    if (dall > BD || (dall == BD && g < BG)) { BD = dall; BG = g; }
                    __syncthreads();
                }
                int mf = more_flag;
                __syncthreads();
                if (!mf) break;
            }
            winner = BG;
        }
        if (tid == 0) fi[it] = winner;
        winner = __builtin_amdgcn_readfirstlane(winner);
        // seed broadcast: x,y via LDS broadcast read; z via scalar global load
        float2 wxy = sxy[winner];
        sx = wxy.x;
        sy = wxy.y;
        sz = pts[winner * 3 + 2];
    }
}

// ---------------------------------------------------------------------------
// Gathers: write sampled coords (exact bit copies) + compose original indices.
// ---------------------------------------------------------------------------
__global__ void gather0_kernel(const float* __restrict__ pts,
                               const int* __restrict__ fi0,
                               float* __restrict__ sp0) {
    int t = blockIdx.x * 256 + threadIdx.x;
    if (t >= 4096) return;
    int g = fi0[t];
    sp0[t * 3 + 0] = pts[g * 3 + 0];
    sp0[t * 3 + 1] = pts[g * 3 + 1];
    sp0[t * 3 + 2] = pts[g * 3 + 2];
}

__global__ void gather_next_kernel(const float* __restrict__ pts,
                                   const int* __restrict__ prev_orig,
                                   const int* __restrict__ fi, int S,
                                   float* __restrict__ sp,
                                   int* __restrict__ orig_out) {
    int t = blockIdx.x * 256 + threadIdx.x;
    if (t >= S) return;
    int f = fi[t];
    int g = prev_orig[f];
    orig_out[t] = g;
    sp[t * 3 + 0] = pts[g * 3 + 0];
    sp[t * 3 + 1] = pts[g * 3 + 1];
    sp[t * 3 + 2] = pts[g * 3 + 2];
}

// ---------------------------------------------------------------------------
// Per-scale MLP: lf = relu(sf @ mw1 + mb1) @ mw2 + mb2.
// ---------------------------------------------------------------------------
__global__ __launch_bounds__(256) void mlp_kernel(
    const float* __restrict__ feats, const int* __restrict__ orig,
    const float* __restrict__ mw1, const float* __restrict__ mb1,
    const float* __restrict__ mw2, const float* __restrict__ mb2,
    float* __restrict__ out) {
    __shared__ float sfl[64], h1l[128];
    const int t = threadIdx.x;
    for (int pl = 0; pl < 16; ++pl) {
        const int p = blockIdx.x * 16 + pl;
        const int g = orig[p];
        if (t < 64) sfl[t] = feats[g * 64 + t];
        __syncthreads();
        if (t < 128) {
            float h = mb1[t];
            for (int dd = 0; dd < 64; ++dd)
                h = fmaf(sfl[dd], mw1[dd * 128 + t], h);
            h1l[t] = fmaxf(h, 0.0f);
        }
        __syncthreads();
        float o = mb2[t];
        for (int dd = 0; dd < 128; ++dd)
            o = fmaf(h1l[dd], mw2[dd * 256 + t], o);
        out[p * 256 + t] = o;
        __syncthreads();
    }
}

// ---------------------------------------------------------------------------
extern "C" void kernel_launch(void* const* d_in, const int* in_sizes, int n_in,
                              void* d_out, int out_size, void* d_ws, size_t ws_size,
                              hipStream_t stream) {
    const float* pts = (const float*)d_in[0];
    const float* ew1 = (const float*)d_in[1];
    const float* eb1 = (const float*)d_in[2];
    const float* ew2 = (const float*)d_in[3];
    const float* eb2 = (const float*)d_in[4];
    const float* mw1 = (const float*)d_in[5];  // (3,64,128)
    const float* mb1 = (const float*)d_in[6];  // (3,128)
    const float* mw2 = (const float*)d_in[7];  // (3,128,256)
    const float* mb2 = (const float*)d_in[8];  // (3,256)
    float* out = (float*)d_out;
    char* ws = (char*)d_ws;

    int* knn = (int*)(ws + 0);
    float* feats = (float*)(ws + 1048576);
    int* fi0 = (int*)(ws + 5242880);
    int* fi1 = (int*)(ws + 5259264);
    int* fi2 = (int*)(ws + 5263360);
    int* orig1 = (int*)(ws + 5264384);
    int* orig2 = (int*)(ws + 5268480);

    float* sp0 = out + 0;
    float* lf0 = out + 12288;
    float* sp1 = out + 1060864;
    float* lf1 = out + 1063936;
    float* sp2 = out + 1326080;
    float* lf2 = out + 1326848;

    knn_kernel<<<N_PTS / 4, 256, 0, stream>>>(pts, knn);
    edgeconv_kernel<<<N_PTS / 4, 256, 0, stream>>>(pts, knn, ew1, eb1, ew2, eb2, feats);

    // scale 0: FPS over 16384 -> 4096
    fps_kernel<512, 32><<<1, 512, 0, stream>>>(pts, 4096, fi0);
    gather0_kernel<<<16, 256, 0, stream>>>(pts, fi0, sp0);
    mlp_kernel<<<4096 / 16, 256, 0, stream>>>(feats, fi0, mw1 + 0 * 8192, mb1 + 0 * 128,
                                              mw2 + 0 * 32768, mb2 + 0 * 256, lf0);

    // scale 1: FPS over sp0 (4096) -> 1024
    fps_kernel<512, 8><<<1, 512, 0, stream>>>(sp0, 1024, fi1);
    gather_next_kernel<<<4, 256, 0, stream>>>(pts, fi0, fi1, 1024, sp1, orig1);
    mlp_kernel<<<1024 / 16, 256, 0, stream>>>(feats, orig1, mw1 + 1 * 8192, mb1 + 1 * 128,
                                              mw2 + 1 * 32768, mb2 + 1 * 256, lf1);

    // scale 2: FPS over sp1 (1024) -> 256
    fps_kernel<512, 2><<<1, 512, 0, stream>>>(sp1, 256, fi2);
    gather_next_kernel<<<1, 256, 0, stream>>>(pts, orig1, fi2, 256, sp2, orig2);
    mlp_kernel<<<256 / 16, 256, 0, stream>>>(feats, orig2, mw1 + 2 * 8192, mb1 + 2 * 128,
                                             mw2 + 2 * 32768, mb2 + 2 * 256, lf2);
}

// Round 6
// 10926.133 us; speedup vs baseline: 1.1834x; 1.1834x over previous
//
#include <hip/hip_runtime.h>
#include <cfloat>
#include <cstdint>

#define N_PTS 16384
#define KNN_K 16
#define KNN_TILE 512
#define CERT_EPS 3e-6f

// ---------------------------------------------------------------------------
// FPS shared-memory block (per scale-N instantiation).
// ---------------------------------------------------------------------------
template <int N>
struct FpsSmem {
    float2 sxy[N];                      // x,y coords (z stays in registers)
    unsigned long long slots[2][8];     // per-wave packed argmax, parity dbuf
    int cw[2][8];                       // per-wave count of m1 >= thr
    int wf[2];                          // winner-thread m2 >= thr flag
    int cand_idx[64];
    int cand_cnt;
    int more_flag;
    double red_d[8];
};

// ---------------------------------------------------------------------------
// FPS v6 body: T=512 threads, P=n/512 pts/thread. Scan numerics bitwise
// identical to validated R5 (certified fp32, direct form, per-thread top-2).
// Argmax reduce: packed-key (f32bits(m1)<<32 | ~g1) per-wave LDS atomicMax
// (fire-and-forget) -> barrier -> 8-slot merge. Certification: fallback iff
// (#threads with m1>=thr) > 1 OR winner-thread m2>=thr  == validated M2>=thr.
// Cooperative exact fp64 fallback verbatim from validated R3/R5.
// ---------------------------------------------------------------------------
template <int P, int N>
__device__ __forceinline__ void fps_body(FpsSmem<N>& sm, const float* __restrict__ pts,
                                         int n_out, int* __restrict__ fi) {
    const int tid = threadIdx.x;
    const int wave = tid >> 6, lane = tid & 63;

    float zr[P], c[P];
#pragma unroll
    for (int q = 0; q < P; ++q) {
        const int g = tid + q * 512;
        float x = pts[g * 3 + 0];
        float y = pts[g * 3 + 1];
        zr[q] = pts[g * 3 + 2];
        sm.sxy[g] = make_float2(x, y);
        c[q] = FLT_MAX;
    }
    if (tid < 16) sm.slots[tid >> 3][tid & 7] = 0ull;
    float sx = pts[0], sy = pts[1], sz = pts[2];
    if (tid == 0) fi[0] = 0;
    __syncthreads();

    for (int it = 1; it < n_out; ++it) {
        // fused min-update + per-thread top-2 (validated numerics, verbatim)
        float m1 = -1.0f, m2 = -1.0f;
        int g1 = 0x7fffffff;
#pragma unroll
        for (int q = 0; q < P; ++q) {
            float2 xy = sm.sxy[tid + q * 512];
            float dx = xy.x - sx, dy = xy.y - sy, dz = zr[q] - sz;
            float t = fmaf(dx, dx, fmaf(dy, dy, dz * dz));
            float nc = fminf(c[q], t);
            c[q] = nc;
            bool gt = nc > m1;
            m2 = fmaxf(m2, fminf(nc, m1));
            m1 = fmaxf(m1, nc);
            g1 = gt ? (tid + q * 512) : g1;
        }
        const int par = it & 1;
        unsigned long long key =
            ((unsigned long long)__float_as_uint(m1) << 32) |
            (unsigned long long)(~(unsigned)g1);
        atomicMax(&sm.slots[par][wave], key);
        __syncthreads();
        unsigned long long best = sm.slots[par][0];
#pragma unroll
        for (int w = 1; w < 8; ++w) {
            unsigned long long v = sm.slots[par][w];
            if (v > best) best = v;
        }
        float M1 = __uint_as_float((unsigned)(best >> 32));
        int G1 = (int)(~(unsigned)best);
        float2 wxy = sm.sxy[G1];          // prefetch winner x,y (LDS)
        float wz = pts[G1 * 3 + 2];       // prefetch winner z (L1-hot global)
        if (lane == 0) sm.slots[par ^ 1][wave] = 0ull;  // reset other parity
        const float thr = M1 - M1 * CERT_EPS;
        unsigned long long bal = __ballot(m1 >= thr);
        if (lane == 0) sm.cw[par][wave] = __popcll(bal);
        if (g1 == G1) sm.wf[par] = (m2 >= thr) ? 1 : 0;  // exactly one thread
        __syncthreads();
        int total = sm.cw[par][0];
#pragma unroll
        for (int w = 1; w < 8; ++w) total += sm.cw[par][w];
        int winner = G1;
        if (total > 1 || sm.wf[par]) {
            // ---- cooperative exact fp64 fallback (uniform branch, verbatim) ----
            unsigned miss = 0;
#pragma unroll
            for (int q = 0; q < P; ++q)
                if (c[q] >= thr) miss |= (1u << q);
            double BD = -1.0;
            int BG = 0x7fffffff;
            for (;;) {
                if (tid == 0) { sm.cand_cnt = 0; sm.more_flag = 0; }
                __syncthreads();
#pragma unroll
                for (int q = 0; q < P; ++q) {
                    if (miss & (1u << q)) {
                        int slot = atomicAdd(&sm.cand_cnt, 1);
                        if (slot < 64) {
                            sm.cand_idx[slot] = tid + q * 512;
                            miss &= ~(1u << q);
                        } else {
                            sm.more_flag = 1;
                        }
                    }
                }
                __syncthreads();
                int ncand = sm.cand_cnt;
                if (ncand > 64) ncand = 64;
                for (int ci = 0; ci < ncand; ++ci) {
                    const int g = sm.cand_idx[ci];
                    const double qx = (double)pts[g * 3 + 0];
                    const double qy = (double)pts[g * 3 + 1];
                    const double qz = (double)pts[g * 3 + 2];
                    double dmin = DBL_MAX;
                    for (int i = tid; i < it; i += 512) {
                        const int h = fi[i];
                        double ddx = qx - (double)pts[h * 3 + 0];
                        double ddy = qy - (double)pts[h * 3 + 1];
                        double ddz = qz - (double)pts[h * 3 + 2];
                        double dd = ddx * ddx + ddy * ddy + ddz * ddz;
                        dmin = (dd < dmin) ? dd : dmin;
                    }
                    for (int off = 32; off; off >>= 1) {
                        double od = __shfl_xor(dmin, off);
                        dmin = (od < dmin) ? od : dmin;
                    }
                    if (lane == 0) sm.red_d[wave] = dmin;
                    __syncthreads();
                    double dall = sm.red_d[0];
#pragma unroll
                    for (int w = 1; w < 8; ++w) dall = (sm.red_d[w] < dall) ? sm.red_d[w] : dall;
                    if (dall > BD || (dall == BD && g < BG)) { BD = dall; BG = g; }
                    __syncthreads();
                }
                int mf = sm.more_flag;
                __syncthreads();
                if (!mf) break;
            }
            winner = BG;
            wxy = sm.sxy[winner];
            wz = pts[winner * 3 + 2];
        }
        if (tid == 0) fi[it] = winner;
        sx = wxy.x; sy = wxy.y; sz = wz;
    }
}

// ---------------------------------------------------------------------------
// Fused KNN + EdgeConv body: 512 threads = 8 waves = 8 query points.
// Per-wave fp64-exact top-16 (verbatim numerics), then edgeconv inline in
// merge order (bitwise-same neighbor sequence and arithmetic as the
// validated separate kernels; no knn array round-trip).
// ---------------------------------------------------------------------------
struct KnnSmem {
    float sx[KNN_TILE], sy[KNN_TILE], sz[KNN_TILE];
    float w1[6 * 64], b1v[64], w2[64 * 64], b2v[64];
};

__device__ __forceinline__ void knn_edge_body(
    KnnSmem& sm, const float* __restrict__ pts,
    const float* __restrict__ ew1, const float* __restrict__ eb1,
    const float* __restrict__ ew2, const float* __restrict__ eb2,
    float* __restrict__ feats, int qb) {
    // stage MLP weights once (read only after the tile loop's barriers)
    for (int t = threadIdx.x; t < 6 * 64; t += 512) sm.w1[t] = ew1[t];
    for (int t = threadIdx.x; t < 64; t += 512) { sm.b1v[t] = eb1[t]; sm.b2v[t] = eb2[t]; }
    for (int t = threadIdx.x; t < 64 * 64; t += 512) sm.w2[t] = ew2[t];

    const int wave = threadIdx.x >> 6;
    const int lane = threadIdx.x & 63;
    const int qi = qb * 8 + wave;
    const double qxd = (double)pts[qi * 3 + 0];
    const double qyd = (double)pts[qi * 3 + 1];
    const double qzd = (double)pts[qi * 3 + 2];

    double ld[16];
    int li[16];
#pragma unroll
    for (int s = 0; s < 16; ++s) { ld[s] = DBL_MAX; li[s] = 0x7fffffff; }
    double md = DBL_MAX; int mj = 0x7fffffff; int mslot = 0;

    for (int t0 = 0; t0 < N_PTS; t0 += KNN_TILE) {
        __syncthreads();
        for (int t = threadIdx.x; t < KNN_TILE; t += 512) {
            sm.sx[t] = pts[(t0 + t) * 3 + 0];
            sm.sy[t] = pts[(t0 + t) * 3 + 1];
            sm.sz[t] = pts[(t0 + t) * 3 + 2];
        }
        __syncthreads();
#pragma unroll
        for (int m = 0; m < KNN_TILE / 64; ++m) {
            const int cc = lane + m * 64;
            const int j = t0 + cc;
            if (j == qi) continue;  // diagonal excluded (d=inf in reference)
            double dx = qxd - (double)sm.sx[cc];
            double dy = qyd - (double)sm.sy[cc];
            double dz = qzd - (double)sm.sz[cc];
            double dd = dx * dx + dy * dy + dz * dz;
            if (dd < md || (dd == md && j < mj)) {
#pragma unroll
                for (int s = 0; s < 16; ++s)
                    if (s == mslot) { ld[s] = dd; li[s] = j; }
                md = -1.0; mj = -1; mslot = 0;
#pragma unroll
                for (int s = 0; s < 16; ++s) {
                    bool g = (ld[s] > md) || (ld[s] == md && li[s] > mj);
                    if (g) { md = ld[s]; mj = li[s]; mslot = s; }
                }
            }
        }
    }

    // fused merge (extract-min rounds) + edgeconv, order identical to validated
    const float xi = pts[qi * 3], yi = pts[qi * 3 + 1], zi = pts[qi * 3 + 2];
    float acc = -FLT_MAX;
    for (int r = 0; r < KNN_K; ++r) {
        double cd = DBL_MAX; int cj = 0x7fffffff; int cs = 0;
#pragma unroll
        for (int s = 0; s < 16; ++s) {
            bool l = (ld[s] < cd) || (ld[s] == cd && li[s] < cj);
            if (l) { cd = ld[s]; cj = li[s]; cs = s; }
        }
        double wd = cd; int wj = cj;
        for (int off = 32; off; off >>= 1) {
            double od = __shfl_xor(wd, off);
            int oj = __shfl_xor(wj, off);
            if (od < wd || (od == wd && oj < wj)) { wd = od; wj = oj; }
        }
        if (cd == wd && cj == wj) {
#pragma unroll
            for (int s = 0; s < 16; ++s)
                if (s == cs) { ld[s] = DBL_MAX; li[s] = 0x7fffffff; }
        }
        // edgeconv for neighbor wj (wave-uniform)
        const float xj = pts[wj * 3], yj = pts[wj * 3 + 1], zj = pts[wj * 3 + 2];
        const float f3 = xj - xi, f4 = yj - yi, f5 = zj - zi;
        float h1 = sm.b1v[lane];
        h1 = fmaf(xi, sm.w1[0 * 64 + lane], h1);
        h1 = fmaf(yi, sm.w1[1 * 64 + lane], h1);
        h1 = fmaf(zi, sm.w1[2 * 64 + lane], h1);
        h1 = fmaf(f3, sm.w1[3 * 64 + lane], h1);
        h1 = fmaf(f4, sm.w1[4 * 64 + lane], h1);
        h1 = fmaf(f5, sm.w1[5 * 64 + lane], h1);
        h1 = fmaxf(h1, 0.0f);
        float h2 = sm.b2v[lane];
        for (int d = 0; d < 64; ++d)
            h2 = fmaf(__shfl(h1, d), sm.w2[d * 64 + lane], h2);
        acc = fmaxf(acc, h2);
    }
    feats[qi * 64 + lane] = acc;
}

// ---------------------------------------------------------------------------
// Mega kernel: block 0 = fps scale0 (sole owner of its CU, 132KB LDS);
// blocks 1..2048 = fused knn+edgeconv (runs on the other 255 CUs, hidden
// under fps0's ~4.5 ms).
// ---------------------------------------------------------------------------
__global__ __launch_bounds__(512) void mega_kernel(
    const float* __restrict__ pts,
    const float* __restrict__ ew1, const float* __restrict__ eb1,
    const float* __restrict__ ew2, const float* __restrict__ eb2,
    float* __restrict__ feats, int* __restrict__ fi0) {
    __shared__ __align__(16) char raw[sizeof(FpsSmem<N_PTS>)];
    if (blockIdx.x == 0) {
        fps_body<32, N_PTS>(*reinterpret_cast<FpsSmem<N_PTS>*>(raw), pts, 4096, fi0);
    } else {
        knn_edge_body(*reinterpret_cast<KnnSmem*>(raw), pts, ew1, eb1, ew2, eb2,
                      feats, blockIdx.x - 1);
    }
}

template <int P, int N>
__global__ __launch_bounds__(512) void fps_kernel(const float* __restrict__ pts,
                                                  int n_out, int* __restrict__ fi) {
    __shared__ FpsSmem<N> sm;
    fps_body<P, N>(sm, pts, n_out, fi);
}

// ---------------------------------------------------------------------------
// Gathers: write sampled coords (exact bit copies) + compose original indices.
// ---------------------------------------------------------------------------
__global__ void gather0_kernel(const float* __restrict__ pts,
                               const int* __restrict__ fi0,
                               float* __restrict__ sp0) {
    int t = blockIdx.x * 256 + threadIdx.x;
    if (t >= 4096) return;
    int g = fi0[t];
    sp0[t * 3 + 0] = pts[g * 3 + 0];
    sp0[t * 3 + 1] = pts[g * 3 + 1];
    sp0[t * 3 + 2] = pts[g * 3 + 2];
}

__global__ void gather_next_kernel(const float* __restrict__ pts,
                                   const int* __restrict__ prev_orig,
                                   const int* __restrict__ fi, int S,
                                   float* __restrict__ sp,
                                   int* __restrict__ orig_out) {
    int t = blockIdx.x * 256 + threadIdx.x;
    if (t >= S) return;
    int f = fi[t];
    int g = prev_orig[f];
    orig_out[t] = g;
    sp[t * 3 + 0] = pts[g * 3 + 0];
    sp[t * 3 + 1] = pts[g * 3 + 1];
    sp[t * 3 + 2] = pts[g * 3 + 2];
}

// ---------------------------------------------------------------------------
// Per-scale MLP: lf = relu(sf @ mw1 + mb1) @ mw2 + mb2.
// ---------------------------------------------------------------------------
__global__ __launch_bounds__(256) void mlp_kernel(
    const float* __restrict__ feats, const int* __restrict__ orig,
    const float* __restrict__ mw1, const float* __restrict__ mb1,
    const float* __restrict__ mw2, const float* __restrict__ mb2,
    float* __restrict__ out) {
    __shared__ float sfl[64], h1l[128];
    const int t = threadIdx.x;
    for (int pl = 0; pl < 16; ++pl) {
        const int p = blockIdx.x * 16 + pl;
        const int g = orig[p];
        if (t < 64) sfl[t] = feats[g * 64 + t];
        __syncthreads();
        if (t < 128) {
            float h = mb1[t];
            for (int dd = 0; dd < 64; ++dd)
                h = fmaf(sfl[dd], mw1[dd * 128 + t], h);
            h1l[t] = fmaxf(h, 0.0f);
        }
        __syncthreads();
        float o = mb2[t];
        for (int dd = 0; dd < 128; ++dd)
            o = fmaf(h1l[dd], mw2[dd * 256 + t], o);
        out[p * 256 + t] = o;
        __syncthreads();
    }
}

// ---------------------------------------------------------------------------
extern "C" void kernel_launch(void* const* d_in, const int* in_sizes, int n_in,
                              void* d_out, int out_size, void* d_ws, size_t ws_size,
                              hipStream_t stream) {
    const float* pts = (const float*)d_in[0];
    const float* ew1 = (const float*)d_in[1];
    const float* eb1 = (const float*)d_in[2];
    const float* ew2 = (const float*)d_in[3];
    const float* eb2 = (const float*)d_in[4];
    const float* mw1 = (const float*)d_in[5];  // (3,64,128)
    const float* mb1 = (const float*)d_in[6];  // (3,128)
    const float* mw2 = (const float*)d_in[7];  // (3,128,256)
    const float* mb2 = (const float*)d_in[8];  // (3,256)
    float* out = (float*)d_out;
    char* ws = (char*)d_ws;

    float* feats = (float*)(ws + 0);           // 16384*64*4 = 4 MB
    int* fi0 = (int*)(ws + 4194304);           // 4096 ints
    int* fi1 = (int*)(ws + 4210688);           // 1024 ints
    int* fi2 = (int*)(ws + 4214784);           // 256 ints
    int* orig1 = (int*)(ws + 4215808);         // 1024 ints
    int* orig2 = (int*)(ws + 4219904);         // 256 ints

    float* sp0 = out + 0;
    float* lf0 = out + 12288;
    float* sp1 = out + 1060864;
    float* lf1 = out + 1063936;
    float* sp2 = out + 1326080;
    float* lf2 = out + 1326848;

    // fps scale0 (block 0) co-scheduled with fused knn+edgeconv (blocks 1..2048)
    mega_kernel<<<1 + N_PTS / 8, 512, 0, stream>>>(pts, ew1, eb1, ew2, eb2, feats, fi0);

    gather0_kernel<<<16, 256, 0, stream>>>(pts, fi0, sp0);
    mlp_kernel<<<4096 / 16, 256, 0, stream>>>(feats, fi0, mw1 + 0 * 8192, mb1 + 0 * 128,
                                              mw2 + 0 * 32768, mb2 + 0 * 256, lf0);

    // scale 1: FPS over sp0 (4096) -> 1024
    fps_kernel<8, 4096><<<1, 512, 0, stream>>>(sp0, 1024, fi1);
    gather_next_kernel<<<4, 256, 0, stream>>>(pts, fi0, fi1, 1024, sp1, orig1);
    mlp_kernel<<<1024 / 16, 256, 0, stream>>>(feats, orig1, mw1 + 1 * 8192, mb1 + 1 * 128,
                                              mw2 + 1 * 32768, mb2 + 1 * 256, lf1);

    // scale 2: FPS over sp1 (1024) -> 256
    fps_kernel<2, 1024><<<1, 512, 0, stream>>>(sp1, 256, fi2);
    gather_next_kernel<<<1, 256, 0, stream>>>(pts, orig1, fi2, 256, sp2, orig2);
    mlp_kernel<<<256 / 16, 256, 0, stream>>>(feats, orig2, mw1 + 2 * 8192, mb1 + 2 * 128,
                                             mw2 + 2 * 32768, mb2 + 2 * 256, lf2);
}

// Round 7
// 10462.061 us; speedup vs baseline: 1.2359x; 1.0444x over previous
//
#include <hip/hip_runtime.h>
#include <cfloat>
#include <cstdint>

#define N_PTS 16384
#define KNN_K 16
#define KNN_TILE 512
#define CERT_EPS 3e-6f

// ---------------------------------------------------------------------------
// FPS shared-memory block (per scale-N instantiation).
// ---------------------------------------------------------------------------
template <int N>
struct FpsSmem {
    float2 sxy[N];                      // x,y coords (z stays in registers)
    unsigned long long slots[2][16];    // packed argmax, lane&15-spread, parity dbuf
    int cw[2][16];                      // per-wave count of m1 >= thr
    int wf[2];                          // winner-thread m2 >= thr flag
    float4 win[2];                      // winner xyz broadcast
    int cand_idx[64];
    int cand_cnt;
    int more_flag;
    double red_d[16];
};

// ---------------------------------------------------------------------------
// FPS v7 body: T=1024 threads (16 waves, 4/SIMD for latency hiding),
// P = n/T pts/thread. Scan numerics bitwise identical to validated R5/R6
// (certified fp32, direct form, per-thread top-2). Argmax reduce: packed-key
// (f32bits(m1)<<32 | ~g1) atomicMax spread over 16 LDS slots (tid&15 => max
// 4-way same-address serialization). Winner thread publishes xyz between the
// two barriers (z from its own register). Certification: fallback iff
// (#threads with m1>=thr) > 1 OR winner-thread m2>=thr == validated M2>=thr.
// Cooperative exact fp64 fallback verbatim (strides T).
// ---------------------------------------------------------------------------
template <int T, int P, int N>
__device__ __forceinline__ void fps_body(FpsSmem<N>& sm, const float* __restrict__ pts,
                                         int n_out, int* __restrict__ fi) {
    constexpr int NW = T / 64;
    const int tid = threadIdx.x;
    const int wave = tid >> 6, lane = tid & 63;

    float zr[P], c[P];
#pragma unroll
    for (int q = 0; q < P; ++q) {
        const int g = tid + q * T;
        float x = pts[g * 3 + 0];
        float y = pts[g * 3 + 1];
        zr[q] = pts[g * 3 + 2];
        sm.sxy[g] = make_float2(x, y);
        c[q] = FLT_MAX;
    }
    if (tid < 32) sm.slots[tid >> 4][tid & 15] = 0ull;
    float sx = pts[0], sy = pts[1], sz = pts[2];
    if (tid == 0) fi[0] = 0;
    __syncthreads();

    for (int it = 1; it < n_out; ++it) {
        // fused min-update + per-thread top-2 (validated numerics, verbatim)
        float m1 = -1.0f, m2 = -1.0f;
        int g1 = 0x7fffffff;
#pragma unroll
        for (int q = 0; q < P; ++q) {
            float2 xy = sm.sxy[tid + q * T];
            float dx = xy.x - sx, dy = xy.y - sy, dz = zr[q] - sz;
            float t = fmaf(dx, dx, fmaf(dy, dy, dz * dz));
            float nc = fminf(c[q], t);
            c[q] = nc;
            bool gt = nc > m1;
            m2 = fmaxf(m2, fminf(nc, m1));
            m1 = fmaxf(m1, nc);
            g1 = gt ? (tid + q * T) : g1;
        }
        const int par = it & 1;
        unsigned long long key =
            ((unsigned long long)__float_as_uint(m1) << 32) |
            (unsigned long long)(~(unsigned)g1);
        atomicMax(&sm.slots[par][tid & 15], key);
        __syncthreads();
        unsigned long long best = sm.slots[par][0];
#pragma unroll
        for (int w = 1; w < 16; ++w) {
            unsigned long long v = sm.slots[par][w];
            if (v > best) best = v;
        }
        const float M1 = __uint_as_float((unsigned)(best >> 32));
        const int G1 = (int)(~(unsigned)best);
        if (tid < 16) sm.slots[par ^ 1][tid] = 0ull;  // reset other parity
        const float thr = M1 - M1 * CERT_EPS;
        unsigned long long bal = __ballot(m1 >= thr);
        if (lane == 0) sm.cw[par][wave] = __popcll(bal);
        if (g1 == G1) {  // exactly one thread (disjoint point ownership)
            sm.wf[par] = (m2 >= thr) ? 1 : 0;
            const int qw = (g1 - tid) / T;
            float zw = 0.0f;
#pragma unroll
            for (int q = 0; q < P; ++q)
                if (q == qw) zw = zr[q];
            float2 xy = sm.sxy[g1];
            sm.win[par] = make_float4(xy.x, xy.y, zw, 0.0f);
        }
        __syncthreads();
        int total = sm.cw[par][0];
#pragma unroll
        for (int w = 1; w < NW; ++w) total += sm.cw[par][w];
        int winner = G1;
        float4 wv = sm.win[par];
        if (total > 1 || sm.wf[par]) {
            // ---- cooperative exact fp64 fallback (uniform branch, verbatim) ----
            unsigned miss = 0;
#pragma unroll
            for (int q = 0; q < P; ++q)
                if (c[q] >= thr) miss |= (1u << q);
            double BD = -1.0;
            int BG = 0x7fffffff;
            for (;;) {
                if (tid == 0) { sm.cand_cnt = 0; sm.more_flag = 0; }
                __syncthreads();
#pragma unroll
                for (int q = 0; q < P; ++q) {
                    if (miss & (1u << q)) {
                        int slot = atomicAdd(&sm.cand_cnt, 1);
                        if (slot < 64) {
                            sm.cand_idx[slot] = tid + q * T;
                            miss &= ~(1u << q);
                        } else {
                            sm.more_flag = 1;
                        }
                    }
                }
                __syncthreads();
                int ncand = sm.cand_cnt;
                if (ncand > 64) ncand = 64;
                for (int ci = 0; ci < ncand; ++ci) {
                    const int g = sm.cand_idx[ci];
                    const double qx = (double)pts[g * 3 + 0];
                    const double qy = (double)pts[g * 3 + 1];
                    const double qz = (double)pts[g * 3 + 2];
                    double dmin = DBL_MAX;
                    for (int i = tid; i < it; i += T) {
                        const int h = fi[i];
                        double ddx = qx - (double)pts[h * 3 + 0];
                        double ddy = qy - (double)pts[h * 3 + 1];
                        double ddz = qz - (double)pts[h * 3 + 2];
                        double dd = ddx * ddx + ddy * ddy + ddz * ddz;
                        dmin = (dd < dmin) ? dd : dmin;
                    }
                    for (int off = 32; off; off >>= 1) {
                        double od = __shfl_xor(dmin, off);
                        dmin = (od < dmin) ? od : dmin;
                    }
                    if (lane == 0) sm.red_d[wave] = dmin;
                    __syncthreads();
                    double dall = sm.red_d[0];
#pragma unroll
                    for (int w = 1; w < NW; ++w) dall = (sm.red_d[w] < dall) ? sm.red_d[w] : dall;
                    if (dall > BD || (dall == BD && g < BG)) { BD = dall; BG = g; }
                    __syncthreads();
                }
                int mf = sm.more_flag;
                __syncthreads();
                if (!mf) break;
            }
            winner = BG;
            float2 xy = sm.sxy[winner];
            wv = make_float4(xy.x, xy.y, pts[winner * 3 + 2], 0.0f);
        }
        if (tid == 0) fi[it] = winner;
        sx = wv.x; sy = wv.y; sz = wv.z;
    }
}

// ---------------------------------------------------------------------------
// Fused KNN + EdgeConv body: 1024 threads = 16 waves = 16 query points.
// Per-wave fp64-exact top-16 (verbatim numerics), then edgeconv inline in
// merge order (bitwise-same neighbor sequence and arithmetic as validated).
// ---------------------------------------------------------------------------
struct KnnSmem {
    float sx[KNN_TILE], sy[KNN_TILE], sz[KNN_TILE];
    float w1[6 * 64], b1v[64], w2[64 * 64], b2v[64];
};

__device__ __forceinline__ void knn_edge_body(
    KnnSmem& sm, const float* __restrict__ pts,
    const float* __restrict__ ew1, const float* __restrict__ eb1,
    const float* __restrict__ ew2, const float* __restrict__ eb2,
    float* __restrict__ feats, int qb) {
    for (int t = threadIdx.x; t < 6 * 64; t += 1024) sm.w1[t] = ew1[t];
    for (int t = threadIdx.x; t < 64; t += 1024) { sm.b1v[t] = eb1[t]; sm.b2v[t] = eb2[t]; }
    for (int t = threadIdx.x; t < 64 * 64; t += 1024) sm.w2[t] = ew2[t];

    const int wave = threadIdx.x >> 6;
    const int lane = threadIdx.x & 63;
    const int qi = qb * 16 + wave;
    const double qxd = (double)pts[qi * 3 + 0];
    const double qyd = (double)pts[qi * 3 + 1];
    const double qzd = (double)pts[qi * 3 + 2];

    double ld[16];
    int li[16];
#pragma unroll
    for (int s = 0; s < 16; ++s) { ld[s] = DBL_MAX; li[s] = 0x7fffffff; }
    double md = DBL_MAX; int mj = 0x7fffffff; int mslot = 0;

    for (int t0 = 0; t0 < N_PTS; t0 += KNN_TILE) {
        __syncthreads();
        for (int t = threadIdx.x; t < KNN_TILE; t += 1024) {
            sm.sx[t] = pts[(t0 + t) * 3 + 0];
            sm.sy[t] = pts[(t0 + t) * 3 + 1];
            sm.sz[t] = pts[(t0 + t) * 3 + 2];
        }
        __syncthreads();
#pragma unroll
        for (int m = 0; m < KNN_TILE / 64; ++m) {
            const int cc = lane + m * 64;
            const int j = t0 + cc;
            if (j == qi) continue;  // diagonal excluded (d=inf in reference)
            double dx = qxd - (double)sm.sx[cc];
            double dy = qyd - (double)sm.sy[cc];
            double dz = qzd - (double)sm.sz[cc];
            double dd = dx * dx + dy * dy + dz * dz;
            if (dd < md || (dd == md && j < mj)) {
#pragma unroll
                for (int s = 0; s < 16; ++s)
                    if (s == mslot) { ld[s] = dd; li[s] = j; }
                md = -1.0; mj = -1; mslot = 0;
#pragma unroll
                for (int s = 0; s < 16; ++s) {
                    bool g = (ld[s] > md) || (ld[s] == md && li[s] > mj);
                    if (g) { md = ld[s]; mj = li[s]; mslot = s; }
                }
            }
        }
    }

    const float xi = pts[qi * 3], yi = pts[qi * 3 + 1], zi = pts[qi * 3 + 2];
    float acc = -FLT_MAX;
    for (int r = 0; r < KNN_K; ++r) {
        double cd = DBL_MAX; int cj = 0x7fffffff; int cs = 0;
#pragma unroll
        for (int s = 0; s < 16; ++s) {
            bool l = (ld[s] < cd) || (ld[s] == cd && li[s] < cj);
            if (l) { cd = ld[s]; cj = li[s]; cs = s; }
        }
        double wd = cd; int wj = cj;
        for (int off = 32; off; off >>= 1) {
            double od = __shfl_xor(wd, off);
            int oj = __shfl_xor(wj, off);
            if (od < wd || (od == wd && oj < wj)) { wd = od; wj = oj; }
        }
        if (cd == wd && cj == wj) {
#pragma unroll
            for (int s = 0; s < 16; ++s)
                if (s == cs) { ld[s] = DBL_MAX; li[s] = 0x7fffffff; }
        }
        const float xj = pts[wj * 3], yj = pts[wj * 3 + 1], zj = pts[wj * 3 + 2];
        const float f3 = xj - xi, f4 = yj - yi, f5 = zj - zi;
        float h1 = sm.b1v[lane];
        h1 = fmaf(xi, sm.w1[0 * 64 + lane], h1);
        h1 = fmaf(yi, sm.w1[1 * 64 + lane], h1);
        h1 = fmaf(zi, sm.w1[2 * 64 + lane], h1);
        h1 = fmaf(f3, sm.w1[3 * 64 + lane], h1);
        h1 = fmaf(f4, sm.w1[4 * 64 + lane], h1);
        h1 = fmaf(f5, sm.w1[5 * 64 + lane], h1);
        h1 = fmaxf(h1, 0.0f);
        float h2 = sm.b2v[lane];
        for (int d = 0; d < 64; ++d)
            h2 = fmaf(__shfl(h1, d), sm.w2[d * 64 + lane], h2);
        acc = fmaxf(acc, h2);
    }
    feats[qi * 64 + lane] = acc;
}

// ---------------------------------------------------------------------------
// Mega kernel: block 0 = fps scale0; blocks 1..1024 = fused knn+edgeconv
// (hidden under fps0).
// ---------------------------------------------------------------------------
__global__ __launch_bounds__(1024) void mega_kernel(
    const float* __restrict__ pts,
    const float* __restrict__ ew1, const float* __restrict__ eb1,
    const float* __restrict__ ew2, const float* __restrict__ eb2,
    float* __restrict__ feats, int* __restrict__ fi0) {
    __shared__ __align__(16) char raw[sizeof(FpsSmem<N_PTS>)];
    if (blockIdx.x == 0) {
        fps_body<1024, 16, N_PTS>(*reinterpret_cast<FpsSmem<N_PTS>*>(raw), pts, 4096, fi0);
    } else {
        knn_edge_body(*reinterpret_cast<KnnSmem*>(raw), pts, ew1, eb1, ew2, eb2,
                      feats, blockIdx.x - 1);
    }
}

template <int P, int N>
__global__ __launch_bounds__(1024) void fps_kernel(const float* __restrict__ pts,
                                                   int n_out, int* __restrict__ fi) {
    __shared__ FpsSmem<N> sm;
    fps_body<1024, P, N>(sm, pts, n_out, fi);
}

// ---------------------------------------------------------------------------
// Gathers: write sampled coords (exact bit copies) + compose original indices.
// ---------------------------------------------------------------------------
__global__ void gather0_kernel(const float* __restrict__ pts,
                               const int* __restrict__ fi0,
                               float* __restrict__ sp0) {
    int t = blockIdx.x * 256 + threadIdx.x;
    if (t >= 4096) return;
    int g = fi0[t];
    sp0[t * 3 + 0] = pts[g * 3 + 0];
    sp0[t * 3 + 1] = pts[g * 3 + 1];
    sp0[t * 3 + 2] = pts[g * 3 + 2];
}

__global__ void gather_next_kernel(const float* __restrict__ pts,
                                   const int* __restrict__ prev_orig,
                                   const int* __restrict__ fi, int S,
                                   float* __restrict__ sp,
                                   int* __restrict__ orig_out) {
    int t = blockIdx.x * 256 + threadIdx.x;
    if (t >= S) return;
    int f = fi[t];
    int g = prev_orig[f];
    orig_out[t] = g;
    sp[t * 3 + 0] = pts[g * 3 + 0];
    sp[t * 3 + 1] = pts[g * 3 + 1];
    sp[t * 3 + 2] = pts[g * 3 + 2];
}

// ---------------------------------------------------------------------------
// Per-scale MLP: lf = relu(sf @ mw1 + mb1) @ mw2 + mb2.
// ---------------------------------------------------------------------------
__global__ __launch_bounds__(256) void mlp_kernel(
    const float* __restrict__ feats, const int* __restrict__ orig,
    const float* __restrict__ mw1, const float* __restrict__ mb1,
    const float* __restrict__ mw2, const float* __restrict__ mb2,
    float* __restrict__ out) {
    __shared__ float sfl[64], h1l[128];
    const int t = threadIdx.x;
    for (int pl = 0; pl < 16; ++pl) {
        const int p = blockIdx.x * 16 + pl;
        const int g = orig[p];
        if (t < 64) sfl[t] = feats[g * 64 + t];
        __syncthreads();
        if (t < 128) {
            float h = mb1[t];
            for (int dd = 0; dd < 64; ++dd)
                h = fmaf(sfl[dd], mw1[dd * 128 + t], h);
            h1l[t] = fmaxf(h, 0.0f);
        }
        __syncthreads();
        float o = mb2[t];
        for (int dd = 0; dd < 128; ++dd)
            o = fmaf(h1l[dd], mw2[dd * 256 + t], o);
        out[p * 256 + t] = o;
        __syncthreads();
    }
}

// ---------------------------------------------------------------------------
extern "C" void kernel_launch(void* const* d_in, const int* in_sizes, int n_in,
                              void* d_out, int out_size, void* d_ws, size_t ws_size,
                              hipStream_t stream) {
    const float* pts = (const float*)d_in[0];
    const float* ew1 = (const float*)d_in[1];
    const float* eb1 = (const float*)d_in[2];
    const float* ew2 = (const float*)d_in[3];
    const float* eb2 = (const float*)d_in[4];
    const float* mw1 = (const float*)d_in[5];  // (3,64,128)
    const float* mb1 = (const float*)d_in[6];  // (3,128)
    const float* mw2 = (const float*)d_in[7];  // (3,128,256)
    const float* mb2 = (const float*)d_in[8];  // (3,256)
    float* out = (float*)d_out;
    char* ws = (char*)d_ws;

    float* feats = (float*)(ws + 0);           // 16384*64*4 = 4 MB
    int* fi0 = (int*)(ws + 4194304);           // 4096 ints
    int* fi1 = (int*)(ws + 4210688);           // 1024 ints
    int* fi2 = (int*)(ws + 4214784);           // 256 ints
    int* orig1 = (int*)(ws + 4215808);         // 1024 ints
    int* orig2 = (int*)(ws + 4219904);         // 256 ints

    float* sp0 = out + 0;
    float* lf0 = out + 12288;
    float* sp1 = out + 1060864;
    float* lf1 = out + 1063936;
    float* sp2 = out + 1326080;
    float* lf2 = out + 1326848;

    // fps scale0 (block 0) co-scheduled with fused knn+edgeconv (blocks 1..1024)
    mega_kernel<<<1 + N_PTS / 16, 1024, 0, stream>>>(pts, ew1, eb1, ew2, eb2, feats, fi0);

    gather0_kernel<<<16, 256, 0, stream>>>(pts, fi0, sp0);
    mlp_kernel<<<4096 / 16, 256, 0, stream>>>(feats, fi0, mw1 + 0 * 8192, mb1 + 0 * 128,
                                              mw2 + 0 * 32768, mb2 + 0 * 256, lf0);

    // scale 1: FPS over sp0 (4096) -> 1024
    fps_kernel<4, 4096><<<1, 1024, 0, stream>>>(sp0, 1024, fi1);
    gather_next_kernel<<<4, 256, 0, stream>>>(pts, fi0, fi1, 1024, sp1, orig1);
    mlp_kernel<<<1024 / 16, 256, 0, stream>>>(feats, orig1, mw1 + 1 * 8192, mb1 + 1 * 128,
                                              mw2 + 1 * 32768, mb2 + 1 * 256, lf1);

    // scale 2: FPS over sp1 (1024) -> 256
    fps_kernel<1, 1024><<<1, 1024, 0, stream>>>(sp1, 256, fi2);
    gather_next_kernel<<<1, 256, 0, stream>>>(pts, orig1, fi2, 256, sp2, orig2);
    mlp_kernel<<<256 / 16, 256, 0, stream>>>(feats, orig2, mw1 + 2 * 8192, mb1 + 2 * 128,
                                             mw2 + 2 * 32768, mb2 + 2 * 256, lf2);
}

// Round 8
// 9818.134 us; speedup vs baseline: 1.3170x; 1.0656x over previous
//
#include <hip/hip_runtime.h>
#include <cfloat>
#include <cstdint>

#define N_PTS 16384
#define KNN_K 16
#define KNN_TILE 512
#define CERT_EPS 3e-6f

// ---------------------------------------------------------------------------
// FPS shared-memory block (sized for the largest scale; reused by all three).
// ---------------------------------------------------------------------------
struct FpsSmem {
    float2 sxy[N_PTS];                  // x,y coords (z stays in registers)
    unsigned long long slots[2][16];    // packed argmax, tid&15-spread, parity dbuf
    int cw[2][16];                      // per-wave count of m1 >= thr
    int wf[2];                          // winner-thread m2 >= thr flag
    float4 win[2];                      // winner xyz broadcast
    int cand_idx[64];
    int cand_cnt;
    int more_flag;
    double red_d[16];
};

// ---------------------------------------------------------------------------
// FPS v8 body: T=1024 threads, P pts/thread (scan set = T*P). IND=true means
// point g's coords are pts[idx[g]] (subset stage); fi[] ALWAYS receives
// ORIGINAL point indices, so fallback history & downstream MLP gathers are
// stage-agnostic. Scan numerics bitwise identical to validated R5-R7
// (certified fp32, direct form, per-thread top-2). Argmax: packed-key
// atomicMax over 16 LDS slots; winner thread publishes xyz between barriers.
// Certification: fallback iff (#threads m1>=thr) > 1 OR winner m2>=thr
// (== validated M2>=thr). Cooperative exact fp64 fallback verbatim.
// ---------------------------------------------------------------------------
template <int T, int P, bool IND>
__device__ __forceinline__ void fps_body(FpsSmem& sm, const float* __restrict__ pts,
                                         const int* __restrict__ idx,
                                         int n_out, int* __restrict__ fi) {
    constexpr int NW = T / 64;
    const int tid = threadIdx.x;
    const int wave = tid >> 6, lane = tid & 63;

    __syncthreads();  // guard sxy/slot reuse against the previous stage's reads

    float zr[P], c[P];
#pragma unroll
    for (int q = 0; q < P; ++q) {
        const int g = tid + q * T;
        const int gg = IND ? idx[g] : g;
        float x = pts[gg * 3 + 0];
        float y = pts[gg * 3 + 1];
        zr[q] = pts[gg * 3 + 2];
        sm.sxy[g] = make_float2(x, y);
        c[q] = FLT_MAX;
    }
    if (tid < 32) sm.slots[tid >> 4][tid & 15] = 0ull;
    const int g0 = IND ? idx[0] : 0;
    float sx = pts[g0 * 3 + 0], sy = pts[g0 * 3 + 1], sz = pts[g0 * 3 + 2];
    if (tid == 0) fi[0] = g0;
    __syncthreads();

    for (int it = 1; it < n_out; ++it) {
        // fused min-update + per-thread top-2 (validated numerics, verbatim)
        float m1 = -1.0f, m2 = -1.0f;
        int g1 = 0x7fffffff;
#pragma unroll
        for (int q = 0; q < P; ++q) {
            float2 xy = sm.sxy[tid + q * T];
            float dx = xy.x - sx, dy = xy.y - sy, dz = zr[q] - sz;
            float t = fmaf(dx, dx, fmaf(dy, dy, dz * dz));
            float nc = fminf(c[q], t);
            c[q] = nc;
            bool gt = nc > m1;
            m2 = fmaxf(m2, fminf(nc, m1));
            m1 = fmaxf(m1, nc);
            g1 = gt ? (tid + q * T) : g1;
        }
        const int par = it & 1;
        unsigned long long key =
            ((unsigned long long)__float_as_uint(m1) << 32) |
            (unsigned long long)(~(unsigned)g1);
        atomicMax(&sm.slots[par][tid & 15], key);
        __syncthreads();
        unsigned long long best = sm.slots[par][0];
#pragma unroll
        for (int w = 1; w < 16; ++w) {
            unsigned long long v = sm.slots[par][w];
            if (v > best) best = v;
        }
        const float M1 = __uint_as_float((unsigned)(best >> 32));
        const int G1 = (int)(~(unsigned)best);
        if (tid < 16) sm.slots[par ^ 1][tid] = 0ull;  // reset other parity
        const float thr = M1 - M1 * CERT_EPS;
        unsigned long long bal = __ballot(m1 >= thr);
        if (lane == 0) sm.cw[par][wave] = __popcll(bal);
        if (g1 == G1) {  // exactly one thread (disjoint point ownership)
            sm.wf[par] = (m2 >= thr) ? 1 : 0;
            const int qw = (g1 - tid) / T;
            float zw = 0.0f;
#pragma unroll
            for (int q = 0; q < P; ++q)
                if (q == qw) zw = zr[q];
            float2 xy = sm.sxy[g1];
            sm.win[par] = make_float4(xy.x, xy.y, zw, 0.0f);
        }
        __syncthreads();
        int total = sm.cw[par][0];
#pragma unroll
        for (int w = 1; w < NW; ++w) total += sm.cw[par][w];
        int winner = G1;
        float4 wv = sm.win[par];
        if (total > 1 || sm.wf[par]) {
            // ---- cooperative exact fp64 fallback (uniform branch, verbatim) ----
            unsigned miss = 0;
#pragma unroll
            for (int q = 0; q < P; ++q)
                if (c[q] >= thr) miss |= (1u << q);
            double BD = -1.0;
            int BG = 0x7fffffff;
            for (;;) {
                if (tid == 0) { sm.cand_cnt = 0; sm.more_flag = 0; }
                __syncthreads();
#pragma unroll
                for (int q = 0; q < P; ++q) {
                    if (miss & (1u << q)) {
                        int slot = atomicAdd(&sm.cand_cnt, 1);
                        if (slot < 64) {
                            sm.cand_idx[slot] = tid + q * T;
                            miss &= ~(1u << q);
                        } else {
                            sm.more_flag = 1;
                        }
                    }
                }
                __syncthreads();
                int ncand = sm.cand_cnt;
                if (ncand > 64) ncand = 64;
                for (int ci = 0; ci < ncand; ++ci) {
                    const int g = sm.cand_idx[ci];
                    const int gg = IND ? idx[g] : g;
                    const double qx = (double)pts[gg * 3 + 0];
                    const double qy = (double)pts[gg * 3 + 1];
                    const double qz = (double)pts[gg * 3 + 2];
                    double dmin = DBL_MAX;
                    for (int i = tid; i < it; i += T) {
                        const int h = fi[i];  // original index, any stage
                        double ddx = qx - (double)pts[h * 3 + 0];
                        double ddy = qy - (double)pts[h * 3 + 1];
                        double ddz = qz - (double)pts[h * 3 + 2];
                        double dd = ddx * ddx + ddy * ddy + ddz * ddz;
                        dmin = (dd < dmin) ? dd : dmin;
                    }
                    for (int off = 32; off; off >>= 1) {
                        double od = __shfl_xor(dmin, off);
                        dmin = (od < dmin) ? od : dmin;
                    }
                    if (lane == 0) sm.red_d[wave] = dmin;
                    __syncthreads();
                    double dall = sm.red_d[0];
#pragma unroll
                    for (int w = 1; w < NW; ++w) dall = (sm.red_d[w] < dall) ? sm.red_d[w] : dall;
                    if (dall > BD || (dall == BD && g < BG)) { BD = dall; BG = g; }
                    __syncthreads();
                }
                int mf = sm.more_flag;
                __syncthreads();
                if (!mf) break;
            }
            winner = BG;
            float2 xy = sm.sxy[winner];
            const int wg = IND ? idx[winner] : winner;
            wv = make_float4(xy.x, xy.y, pts[wg * 3 + 2], 0.0f);
        }
        if (tid == 0) fi[it] = IND ? idx[winner] : winner;
        sx = wv.x; sy = wv.y; sz = wv.z;
    }
}

// ---------------------------------------------------------------------------
// Fused KNN + EdgeConv body: 1024 threads = 16 waves = 16 query points.
// Per-wave fp64-exact top-16 (verbatim validated numerics), edgeconv inline.
// ---------------------------------------------------------------------------
struct KnnSmem {
    float sx[KNN_TILE], sy[KNN_TILE], sz[KNN_TILE];
    float w1[6 * 64], b1v[64], w2[64 * 64], b2v[64];
};

__device__ __forceinline__ void knn_edge_body(
    KnnSmem& sm, const float* __restrict__ pts,
    const float* __restrict__ ew1, const float* __restrict__ eb1,
    const float* __restrict__ ew2, const float* __restrict__ eb2,
    float* __restrict__ feats, int qb) {
    for (int t = threadIdx.x; t < 6 * 64; t += 1024) sm.w1[t] = ew1[t];
    for (int t = threadIdx.x; t < 64; t += 1024) { sm.b1v[t] = eb1[t]; sm.b2v[t] = eb2[t]; }
    for (int t = threadIdx.x; t < 64 * 64; t += 1024) sm.w2[t] = ew2[t];

    const int wave = threadIdx.x >> 6;
    const int lane = threadIdx.x & 63;
    const int qi = qb * 16 + wave;
    const double qxd = (double)pts[qi * 3 + 0];
    const double qyd = (double)pts[qi * 3 + 1];
    const double qzd = (double)pts[qi * 3 + 2];

    double ld[16];
    int li[16];
#pragma unroll
    for (int s = 0; s < 16; ++s) { ld[s] = DBL_MAX; li[s] = 0x7fffffff; }
    double md = DBL_MAX; int mj = 0x7fffffff; int mslot = 0;

    for (int t0 = 0; t0 < N_PTS; t0 += KNN_TILE) {
        __syncthreads();
        for (int t = threadIdx.x; t < KNN_TILE; t += 1024) {
            sm.sx[t] = pts[(t0 + t) * 3 + 0];
            sm.sy[t] = pts[(t0 + t) * 3 + 1];
            sm.sz[t] = pts[(t0 + t) * 3 + 2];
        }
        __syncthreads();
#pragma unroll
        for (int m = 0; m < KNN_TILE / 64; ++m) {
            const int cc = lane + m * 64;
            const int j = t0 + cc;
            if (j == qi) continue;  // diagonal excluded (d=inf in reference)
            double dx = qxd - (double)sm.sx[cc];
            double dy = qyd - (double)sm.sy[cc];
            double dz = qzd - (double)sm.sz[cc];
            double dd = dx * dx + dy * dy + dz * dz;
            if (dd < md || (dd == md && j < mj)) {
#pragma unroll
                for (int s = 0; s < 16; ++s)
                    if (s == mslot) { ld[s] = dd; li[s] = j; }
                md = -1.0; mj = -1; mslot = 0;
#pragma unroll
                for (int s = 0; s < 16; ++s) {
                    bool g = (ld[s] > md) || (ld[s] == md && li[s] > mj);
                    if (g) { md = ld[s]; mj = li[s]; mslot = s; }
                }
            }
        }
    }

    const float xi = pts[qi * 3], yi = pts[qi * 3 + 1], zi = pts[qi * 3 + 2];
    float acc = -FLT_MAX;
    for (int r = 0; r < KNN_K; ++r) {
        double cd = DBL_MAX; int cj = 0x7fffffff; int cs = 0;
#pragma unroll
        for (int s = 0; s < 16; ++s) {
            bool l = (ld[s] < cd) || (ld[s] == cd && li[s] < cj);
            if (l) { cd = ld[s]; cj = li[s]; cs = s; }
        }
        double wd = cd; int wj = cj;
        for (int off = 32; off; off >>= 1) {
            double od = __shfl_xor(wd, off);
            int oj = __shfl_xor(wj, off);
            if (od < wd || (od == wd && oj < wj)) { wd = od; wj = oj; }
        }
        if (cd == wd && cj == wj) {
#pragma unroll
            for (int s = 0; s < 16; ++s)
                if (s == cs) { ld[s] = DBL_MAX; li[s] = 0x7fffffff; }
        }
        const float xj = pts[wj * 3], yj = pts[wj * 3 + 1], zj = pts[wj * 3 + 2];
        const float f3 = xj - xi, f4 = yj - yi, f5 = zj - zi;
        float h1 = sm.b1v[lane];
        h1 = fmaf(xi, sm.w1[0 * 64 + lane], h1);
        h1 = fmaf(yi, sm.w1[1 * 64 + lane], h1);
        h1 = fmaf(zi, sm.w1[2 * 64 + lane], h1);
        h1 = fmaf(f3, sm.w1[3 * 64 + lane], h1);
        h1 = fmaf(f4, sm.w1[4 * 64 + lane], h1);
        h1 = fmaf(f5, sm.w1[5 * 64 + lane], h1);
        h1 = fmaxf(h1, 0.0f);
        float h2 = sm.b2v[lane];
        for (int d = 0; d < 64; ++d)
            h2 = fmaf(__shfl(h1, d), sm.w2[d * 64 + lane], h2);
        acc = fmaxf(acc, h2);
    }
    feats[qi * 64 + lane] = acc;
}

// ---------------------------------------------------------------------------
// Mega kernel: block 0 chains fps0 -> fps1 -> fps2 (subset coords stay
// LDS-resident; fi* hold ORIGINAL indices) and writes sp0/sp1/sp2.
// Blocks 1..1024 = fused knn+edgeconv (hidden under fps).
// amdgpu_waves_per_eu(4,4): forces the 128-VGPR budget (16 waves = 1 block/CU,
// which the 132KB LDS mandates anyway) — R7's 64-VGPR spill (212MB scratch
// writes) is eliminated.
// ---------------------------------------------------------------------------
__global__ __attribute__((amdgpu_waves_per_eu(4, 4))) __launch_bounds__(1024)
void mega_kernel(const float* __restrict__ pts,
                 const float* __restrict__ ew1, const float* __restrict__ eb1,
                 const float* __restrict__ ew2, const float* __restrict__ eb2,
                 float* __restrict__ feats,
                 int* __restrict__ fi0, int* __restrict__ fi1, int* __restrict__ fi2,
                 float* __restrict__ sp0, float* __restrict__ sp1,
                 float* __restrict__ sp2) {
    __shared__ __align__(16) char raw[sizeof(FpsSmem)];
    if (blockIdx.x == 0) {
        FpsSmem& sm = *reinterpret_cast<FpsSmem*>(raw);
        fps_body<1024, 16, false>(sm, pts, nullptr, 4096, fi0);
        fps_body<1024, 4, true>(sm, pts, fi0, 1024, fi1);
        fps_body<1024, 1, true>(sm, pts, fi1, 256, fi2);
        __syncthreads();
        const int tid = threadIdx.x;
        for (int t = tid; t < 4096; t += 1024) {
            int g = fi0[t];
            sp0[t * 3 + 0] = pts[g * 3 + 0];
            sp0[t * 3 + 1] = pts[g * 3 + 1];
            sp0[t * 3 + 2] = pts[g * 3 + 2];
        }
        if (tid < 1024) {
            int g = fi1[tid];
            sp1[tid * 3 + 0] = pts[g * 3 + 0];
            sp1[tid * 3 + 1] = pts[g * 3 + 1];
            sp1[tid * 3 + 2] = pts[g * 3 + 2];
        }
        if (tid < 256) {
            int g = fi2[tid];
            sp2[tid * 3 + 0] = pts[g * 3 + 0];
            sp2[tid * 3 + 1] = pts[g * 3 + 1];
            sp2[tid * 3 + 2] = pts[g * 3 + 2];
        }
    } else {
        knn_edge_body(*reinterpret_cast<KnnSmem*>(raw), pts, ew1, eb1, ew2, eb2,
                      feats, blockIdx.x - 1);
    }
}

// ---------------------------------------------------------------------------
// Tail: all three MLPs in one launch (validated mlp numerics, verbatim).
// ---------------------------------------------------------------------------
__device__ __forceinline__ void mlp_body(
    const float* __restrict__ feats, const int* __restrict__ orig,
    const float* __restrict__ mw1, const float* __restrict__ mb1,
    const float* __restrict__ mw2, const float* __restrict__ mb2,
    float* __restrict__ outp, int pb) {
    __shared__ float sfl[64], h1l[128];
    const int t = threadIdx.x;
    for (int pl = 0; pl < 16; ++pl) {
        const int p = pb * 16 + pl;
        const int g = orig[p];
        if (t < 64) sfl[t] = feats[g * 64 + t];
        __syncthreads();
        if (t < 128) {
            float h = mb1[t];
            for (int dd = 0; dd < 64; ++dd)
                h = fmaf(sfl[dd], mw1[dd * 128 + t], h);
            h1l[t] = fmaxf(h, 0.0f);
        }
        __syncthreads();
        float o = mb2[t];
        for (int dd = 0; dd < 128; ++dd)
            o = fmaf(h1l[dd], mw2[dd * 256 + t], o);
        outp[p * 256 + t] = o;
        __syncthreads();
    }
}

__global__ __launch_bounds__(256) void tail_kernel(
    const float* __restrict__ feats,
    const int* __restrict__ fi0, const int* __restrict__ fi1,
    const int* __restrict__ fi2,
    const float* __restrict__ mw1, const float* __restrict__ mb1,
    const float* __restrict__ mw2, const float* __restrict__ mb2,
    float* __restrict__ out) {
    const int b = blockIdx.x;
    float* lf0 = out + 12288;
    float* lf1 = out + 1063936;
    float* lf2 = out + 1326848;
    if (b < 256) {
        mlp_body(feats, fi0, mw1 + 0 * 8192, mb1 + 0 * 128,
                 mw2 + 0 * 32768, mb2 + 0 * 256, lf0, b);
    } else if (b < 320) {
        mlp_body(feats, fi1, mw1 + 1 * 8192, mb1 + 1 * 128,
                 mw2 + 1 * 32768, mb2 + 1 * 256, lf1, b - 256);
    } else {
        mlp_body(feats, fi2, mw1 + 2 * 8192, mb1 + 2 * 128,
                 mw2 + 2 * 32768, mb2 + 2 * 256, lf2, b - 320);
    }
}

// ---------------------------------------------------------------------------
extern "C" void kernel_launch(void* const* d_in, const int* in_sizes, int n_in,
                              void* d_out, int out_size, void* d_ws, size_t ws_size,
                              hipStream_t stream) {
    const float* pts = (const float*)d_in[0];
    const float* ew1 = (const float*)d_in[1];
    const float* eb1 = (const float*)d_in[2];
    const float* ew2 = (const float*)d_in[3];
    const float* eb2 = (const float*)d_in[4];
    const float* mw1 = (const float*)d_in[5];  // (3,64,128)
    const float* mb1 = (const float*)d_in[6];  // (3,128)
    const float* mw2 = (const float*)d_in[7];  // (3,128,256)
    const float* mb2 = (const float*)d_in[8];  // (3,256)
    float* out = (float*)d_out;
    char* ws = (char*)d_ws;

    float* feats = (float*)(ws + 0);           // 16384*64*4 = 4 MB
    int* fi0 = (int*)(ws + 4194304);           // 4096 ints (original indices)
    int* fi1 = (int*)(ws + 4210688);           // 1024 ints (original indices)
    int* fi2 = (int*)(ws + 4214784);           // 256 ints  (original indices)

    float* sp0 = out + 0;
    float* sp1 = out + 1060864;
    float* sp2 = out + 1326080;

    mega_kernel<<<1 + N_PTS / 16, 1024, 0, stream>>>(pts, ew1, eb1, ew2, eb2, feats,
                                                     fi0, fi1, fi2, sp0, sp1, sp2);
    tail_kernel<<<336, 256, 0, stream>>>(feats, fi0, fi1, fi2, mw1, mb1, mw2, mb2, out);
}

// Round 9
// 9802.183 us; speedup vs baseline: 1.3191x; 1.0016x over previous
//
#include <hip/hip_runtime.h>
#include <cfloat>
#include <cstdint>

#define N_PTS 16384
#define KNN_K 16
#define KNN_TILE 512
#define CERT_EPS 3e-6f

// ---------------------------------------------------------------------------
// FPS shared-memory block (sized for the largest scale; reused by all three).
// ---------------------------------------------------------------------------
struct FpsSmem {
    float2 sxy[N_PTS];                  // x,y coords (z stays in registers)
    unsigned long long slots[2][16];    // packed argmax, tid&15-spread, parity dbuf
    int cw[2][16];                      // per-wave count of m1 >= thr
    int wf[2];                          // winner-thread m2 >= thr flag
    float4 win[2];                      // winner xyz broadcast
    int cand_idx[64];
    int cand_cnt;
    int more_flag;
    double red_d[16];
};

// ---------------------------------------------------------------------------
// FPS v8 body (unchanged from validated R8): T=1024 threads, P pts/thread.
// IND=true -> coords are pts[idx[g]]; fi[] always receives ORIGINAL indices.
// Scan numerics bitwise identical to validated R5-R8. Argmax: packed-key
// atomicMax over 16 LDS slots; winner publishes xyz between barriers.
// Certification: fallback iff (#threads m1>=thr)>1 OR winner m2>=thr
// (== validated M2>=thr). Cooperative exact fp64 fallback verbatim.
// ---------------------------------------------------------------------------
template <int T, int P, bool IND>
__device__ __forceinline__ void fps_body(FpsSmem& sm, const float* __restrict__ pts,
                                         const int* __restrict__ idx,
                                         int n_out, int* __restrict__ fi) {
    constexpr int NW = T / 64;
    const int tid = threadIdx.x;
    const int wave = tid >> 6, lane = tid & 63;

    __syncthreads();  // guard sxy/slot reuse against the previous stage's reads

    float zr[P], c[P];
#pragma unroll
    for (int q = 0; q < P; ++q) {
        const int g = tid + q * T;
        const int gg = IND ? idx[g] : g;
        float x = pts[gg * 3 + 0];
        float y = pts[gg * 3 + 1];
        zr[q] = pts[gg * 3 + 2];
        sm.sxy[g] = make_float2(x, y);
        c[q] = FLT_MAX;
    }
    if (tid < 32) sm.slots[tid >> 4][tid & 15] = 0ull;
    const int g0 = IND ? idx[0] : 0;
    float sx = pts[g0 * 3 + 0], sy = pts[g0 * 3 + 1], sz = pts[g0 * 3 + 2];
    if (tid == 0) fi[0] = g0;
    __syncthreads();

    for (int it = 1; it < n_out; ++it) {
        // fused min-update + per-thread top-2 (validated numerics, verbatim)
        float m1 = -1.0f, m2 = -1.0f;
        int g1 = 0x7fffffff;
#pragma unroll
        for (int q = 0; q < P; ++q) {
            float2 xy = sm.sxy[tid + q * T];
            float dx = xy.x - sx, dy = xy.y - sy, dz = zr[q] - sz;
            float t = fmaf(dx, dx, fmaf(dy, dy, dz * dz));
            float nc = fminf(c[q], t);
            c[q] = nc;
            bool gt = nc > m1;
            m2 = fmaxf(m2, fminf(nc, m1));
            m1 = fmaxf(m1, nc);
            g1 = gt ? (tid + q * T) : g1;
        }
        const int par = it & 1;
        unsigned long long key =
            ((unsigned long long)__float_as_uint(m1) << 32) |
            (unsigned long long)(~(unsigned)g1);
        atomicMax(&sm.slots[par][tid & 15], key);
        __syncthreads();
        unsigned long long best = sm.slots[par][0];
#pragma unroll
        for (int w = 1; w < 16; ++w) {
            unsigned long long v = sm.slots[par][w];
            if (v > best) best = v;
        }
        const float M1 = __uint_as_float((unsigned)(best >> 32));
        const int G1 = (int)(~(unsigned)best);
        if (tid < 16) sm.slots[par ^ 1][tid] = 0ull;  // reset other parity
        const float thr = M1 - M1 * CERT_EPS;
        unsigned long long bal = __ballot(m1 >= thr);
        if (lane == 0) sm.cw[par][wave] = __popcll(bal);
        if (g1 == G1) {  // exactly one thread (disjoint point ownership)
            sm.wf[par] = (m2 >= thr) ? 1 : 0;
            const int qw = (g1 - tid) / T;
            float zw = 0.0f;
#pragma unroll
            for (int q = 0; q < P; ++q)
                if (q == qw) zw = zr[q];
            float2 xy = sm.sxy[g1];
            sm.win[par] = make_float4(xy.x, xy.y, zw, 0.0f);
        }
        __syncthreads();
        int total = sm.cw[par][0];
#pragma unroll
        for (int w = 1; w < NW; ++w) total += sm.cw[par][w];
        int winner = G1;
        float4 wv = sm.win[par];
        if (total > 1 || sm.wf[par]) {
            // ---- cooperative exact fp64 fallback (uniform branch, verbatim) ----
            unsigned miss = 0;
#pragma unroll
            for (int q = 0; q < P; ++q)
                if (c[q] >= thr) miss |= (1u << q);
            double BD = -1.0;
            int BG = 0x7fffffff;
            for (;;) {
                if (tid == 0) { sm.cand_cnt = 0; sm.more_flag = 0; }
                __syncthreads();
#pragma unroll
                for (int q = 0; q < P; ++q) {
                    if (miss & (1u << q)) {
                        int slot = atomicAdd(&sm.cand_cnt, 1);
                        if (slot < 64) {
                            sm.cand_idx[slot] = tid + q * T;
                            miss &= ~(1u << q);
                        } else {
                            sm.more_flag = 1;
                        }
                    }
                }
                __syncthreads();
                int ncand = sm.cand_cnt;
                if (ncand > 64) ncand = 64;
                for (int ci = 0; ci < ncand; ++ci) {
                    const int g = sm.cand_idx[ci];
                    const int gg = IND ? idx[g] : g;
                    const double qx = (double)pts[gg * 3 + 0];
                    const double qy = (double)pts[gg * 3 + 1];
                    const double qz = (double)pts[gg * 3 + 2];
                    double dmin = DBL_MAX;
                    for (int i = tid; i < it; i += T) {
                        const int h = fi[i];  // original index, any stage
                        double ddx = qx - (double)pts[h * 3 + 0];
                        double ddy = qy - (double)pts[h * 3 + 1];
                        double ddz = qz - (double)pts[h * 3 + 2];
                        double dd = ddx * ddx + ddy * ddy + ddz * ddz;
                        dmin = (dd < dmin) ? dd : dmin;
                    }
                    for (int off = 32; off; off >>= 1) {
                        double od = __shfl_xor(dmin, off);
                        dmin = (od < dmin) ? od : dmin;
                    }
                    if (lane == 0) sm.red_d[wave] = dmin;
                    __syncthreads();
                    double dall = sm.red_d[0];
#pragma unroll
                    for (int w = 1; w < NW; ++w) dall = (sm.red_d[w] < dall) ? sm.red_d[w] : dall;
                    if (dall > BD || (dall == BD && g < BG)) { BD = dall; BG = g; }
                    __syncthreads();
                }
                int mf = sm.more_flag;
                __syncthreads();
                if (!mf) break;
            }
            winner = BG;
            float2 xy = sm.sxy[winner];
            const int wg = IND ? idx[winner] : winner;
            wv = make_float4(xy.x, xy.y, pts[wg * 3 + 2], 0.0f);
        }
        if (tid == 0) fi[it] = IND ? idx[winner] : winner;
        sx = wv.x; sy = wv.y; sz = wv.z;
    }
}

// ---------------------------------------------------------------------------
// Fused KNN + EdgeConv body: 1024 threads = 16 waves = 16 query points.
// Per-wave fp64-exact top-16 (verbatim validated numerics), edgeconv inline.
// ---------------------------------------------------------------------------
struct KnnSmem {
    float sx[KNN_TILE], sy[KNN_TILE], sz[KNN_TILE];
    float w1[6 * 64], b1v[64], w2[64 * 64], b2v[64];
};

__device__ __forceinline__ void knn_edge_body(
    KnnSmem& sm, const float* __restrict__ pts,
    const float* __restrict__ ew1, const float* __restrict__ eb1,
    const float* __restrict__ ew2, const float* __restrict__ eb2,
    float* __restrict__ feats, int qb) {
    for (int t = threadIdx.x; t < 6 * 64; t += 1024) sm.w1[t] = ew1[t];
    for (int t = threadIdx.x; t < 64; t += 1024) { sm.b1v[t] = eb1[t]; sm.b2v[t] = eb2[t]; }
    for (int t = threadIdx.x; t < 64 * 64; t += 1024) sm.w2[t] = ew2[t];

    const int wave = threadIdx.x >> 6;
    const int lane = threadIdx.x & 63;
    const int qi = qb * 16 + wave;
    const double qxd = (double)pts[qi * 3 + 0];
    const double qyd = (double)pts[qi * 3 + 1];
    const double qzd = (double)pts[qi * 3 + 2];

    double ld[16];
    int li[16];
#pragma unroll
    for (int s = 0; s < 16; ++s) { ld[s] = DBL_MAX; li[s] = 0x7fffffff; }
    double md = DBL_MAX; int mj = 0x7fffffff; int mslot = 0;

    for (int t0 = 0; t0 < N_PTS; t0 += KNN_TILE) {
        __syncthreads();
        for (int t = threadIdx.x; t < KNN_TILE; t += 1024) {
            sm.sx[t] = pts[(t0 + t) * 3 + 0];
            sm.sy[t] = pts[(t0 + t) * 3 + 1];
            sm.sz[t] = pts[(t0 + t) * 3 + 2];
        }
        __syncthreads();
#pragma unroll
        for (int m = 0; m < KNN_TILE / 64; ++m) {
            const int cc = lane + m * 64;
            const int j = t0 + cc;
            if (j == qi) continue;  // diagonal excluded (d=inf in reference)
            double dx = qxd - (double)sm.sx[cc];
            double dy = qyd - (double)sm.sy[cc];
            double dz = qzd - (double)sm.sz[cc];
            double dd = dx * dx + dy * dy + dz * dz;
            if (dd < md || (dd == md && j < mj)) {
#pragma unroll
                for (int s = 0; s < 16; ++s)
                    if (s == mslot) { ld[s] = dd; li[s] = j; }
                md = -1.0; mj = -1; mslot = 0;
#pragma unroll
                for (int s = 0; s < 16; ++s) {
                    bool g = (ld[s] > md) || (ld[s] == md && li[s] > mj);
                    if (g) { md = ld[s]; mj = li[s]; mslot = s; }
                }
            }
        }
    }

    const float xi = pts[qi * 3], yi = pts[qi * 3 + 1], zi = pts[qi * 3 + 2];
    float acc = -FLT_MAX;
    for (int r = 0; r < KNN_K; ++r) {
        double cd = DBL_MAX; int cj = 0x7fffffff; int cs = 0;
#pragma unroll
        for (int s = 0; s < 16; ++s) {
            bool l = (ld[s] < cd) || (ld[s] == cd && li[s] < cj);
            if (l) { cd = ld[s]; cj = li[s]; cs = s; }
        }
        double wd = cd; int wj = cj;
        for (int off = 32; off; off >>= 1) {
            double od = __shfl_xor(wd, off);
            int oj = __shfl_xor(wj, off);
            if (od < wd || (od == wd && oj < wj)) { wd = od; wj = oj; }
        }
        if (cd == wd && cj == wj) {
#pragma unroll
            for (int s = 0; s < 16; ++s)
                if (s == cs) { ld[s] = DBL_MAX; li[s] = 0x7fffffff; }
        }
        const float xj = pts[wj * 3], yj = pts[wj * 3 + 1], zj = pts[wj * 3 + 2];
        const float f3 = xj - xi, f4 = yj - yi, f5 = zj - zi;
        float h1 = sm.b1v[lane];
        h1 = fmaf(xi, sm.w1[0 * 64 + lane], h1);
        h1 = fmaf(yi, sm.w1[1 * 64 + lane], h1);
        h1 = fmaf(zi, sm.w1[2 * 64 + lane], h1);
        h1 = fmaf(f3, sm.w1[3 * 64 + lane], h1);
        h1 = fmaf(f4, sm.w1[4 * 64 + lane], h1);
        h1 = fmaf(f5, sm.w1[5 * 64 + lane], h1);
        h1 = fmaxf(h1, 0.0f);
        float h2 = sm.b2v[lane];
        for (int d = 0; d < 64; ++d)
            h2 = fmaf(__shfl(h1, d), sm.w2[d * 64 + lane], h2);
        acc = fmaxf(acc, h2);
    }
    feats[qi * 64 + lane] = acc;
}

// ---------------------------------------------------------------------------
// Mega kernel. VGPR-budget pinning: raw LLVM attributes INSTEAD of
// __launch_bounds__ (whose macro emits its own waves-per-eu and silently
// nullified R8's attempt -> VGPR 64, 212MB scratch). flat_work_group_size
// 1024 exact + waves_per_eu(4,4) => 128-VGPR budget; fps (~70) and knn (~80)
// both fit => zero spill.
// Block 0 chains fps0 -> fps1 -> fps2 (coords LDS-resident; fi* = ORIGINAL
// indices) and writes sp0/sp1/sp2. Blocks 1..1024 = fused knn+edgeconv.
// ---------------------------------------------------------------------------
__global__
__attribute__((amdgpu_flat_work_group_size(1024, 1024)))
__attribute__((amdgpu_waves_per_eu(4, 4)))
void mega_kernel(const float* __restrict__ pts,
                 const float* __restrict__ ew1, const float* __restrict__ eb1,
                 const float* __restrict__ ew2, const float* __restrict__ eb2,
                 float* __restrict__ feats,
                 int* __restrict__ fi0, int* __restrict__ fi1, int* __restrict__ fi2,
                 float* __restrict__ sp0, float* __restrict__ sp1,
                 float* __restrict__ sp2) {
    __shared__ __align__(16) char raw[sizeof(FpsSmem)];
    if (blockIdx.x == 0) {
        FpsSmem& sm = *reinterpret_cast<FpsSmem*>(raw);
        fps_body<1024, 16, false>(sm, pts, nullptr, 4096, fi0);
        fps_body<1024, 4, true>(sm, pts, fi0, 1024, fi1);
        fps_body<1024, 1, true>(sm, pts, fi1, 256, fi2);
        __syncthreads();
        const int tid = threadIdx.x;
        for (int t = tid; t < 4096; t += 1024) {
            int g = fi0[t];
            sp0[t * 3 + 0] = pts[g * 3 + 0];
            sp0[t * 3 + 1] = pts[g * 3 + 1];
            sp0[t * 3 + 2] = pts[g * 3 + 2];
        }
        if (tid < 1024) {
            int g = fi1[tid];
            sp1[tid * 3 + 0] = pts[g * 3 + 0];
            sp1[tid * 3 + 1] = pts[g * 3 + 1];
            sp1[tid * 3 + 2] = pts[g * 3 + 2];
        }
        if (tid < 256) {
            int g = fi2[tid];
            sp2[tid * 3 + 0] = pts[g * 3 + 0];
            sp2[tid * 3 + 1] = pts[g * 3 + 1];
            sp2[tid * 3 + 2] = pts[g * 3 + 2];
        }
    } else {
        knn_edge_body(*reinterpret_cast<KnnSmem*>(raw), pts, ew1, eb1, ew2, eb2,
                      feats, blockIdx.x - 1);
    }
}

// ---------------------------------------------------------------------------
// Tail: all three MLPs in one launch (validated mlp numerics, verbatim).
// ---------------------------------------------------------------------------
__device__ __forceinline__ void mlp_body(
    const float* __restrict__ feats, const int* __restrict__ orig,
    const float* __restrict__ mw1, const float* __restrict__ mb1,
    const float* __restrict__ mw2, const float* __restrict__ mb2,
    float* __restrict__ outp, int pb) {
    __shared__ float sfl[64], h1l[128];
    const int t = threadIdx.x;
    for (int pl = 0; pl < 16; ++pl) {
        const int p = pb * 16 + pl;
        const int g = orig[p];
        if (t < 64) sfl[t] = feats[g * 64 + t];
        __syncthreads();
        if (t < 128) {
            float h = mb1[t];
            for (int dd = 0; dd < 64; ++dd)
                h = fmaf(sfl[dd], mw1[dd * 128 + t], h);
            h1l[t] = fmaxf(h, 0.0f);
        }
        __syncthreads();
        float o = mb2[t];
        for (int dd = 0; dd < 128; ++dd)
            o = fmaf(h1l[dd], mw2[dd * 256 + t], o);
        outp[p * 256 + t] = o;
        __syncthreads();
    }
}

__global__ __launch_bounds__(256) void tail_kernel(
    const float* __restrict__ feats,
    const int* __restrict__ fi0, const int* __restrict__ fi1,
    const int* __restrict__ fi2,
    const float* __restrict__ mw1, const float* __restrict__ mb1,
    const float* __restrict__ mw2, const float* __restrict__ mb2,
    float* __restrict__ out) {
    const int b = blockIdx.x;
    float* lf0 = out + 12288;
    float* lf1 = out + 1063936;
    float* lf2 = out + 1326848;
    if (b < 256) {
        mlp_body(feats, fi0, mw1 + 0 * 8192, mb1 + 0 * 128,
                 mw2 + 0 * 32768, mb2 + 0 * 256, lf0, b);
    } else if (b < 320) {
        mlp_body(feats, fi1, mw1 + 1 * 8192, mb1 + 1 * 128,
                 mw2 + 1 * 32768, mb2 + 1 * 256, lf1, b - 256);
    } else {
        mlp_body(feats, fi2, mw1 + 2 * 8192, mb1 + 2 * 128,
                 mw2 + 2 * 32768, mb2 + 2 * 256, lf2, b - 320);
    }
}

// ---------------------------------------------------------------------------
extern "C" void kernel_launch(void* const* d_in, const int* in_sizes, int n_in,
                              void* d_out, int out_size, void* d_ws, size_t ws_size,
                              hipStream_t stream) {
    const float* pts = (const float*)d_in[0];
    const float* ew1 = (const float*)d_in[1];
    const float* eb1 = (const float*)d_in[2];
    const float* ew2 = (const float*)d_in[3];
    const float* eb2 = (const float*)d_in[4];
    const float* mw1 = (const float*)d_in[5];  // (3,64,128)
    const float* mb1 = (const float*)d_in[6];  // (3,128)
    const float* mw2 = (const float*)d_in[7];  // (3,128,256)
    const float* mb2 = (const float*)d_in[8];  // (3,256)
    float* out = (float*)d_out;
    char* ws = (char*)d_ws;

    float* feats = (float*)(ws + 0);           // 16384*64*4 = 4 MB
    int* fi0 = (int*)(ws + 4194304);           // 4096 ints (original indices)
    int* fi1 = (int*)(ws + 4210688);           // 1024 ints (original indices)
    int* fi2 = (int*)(ws + 4214784);           // 256 ints  (original indices)

    float* sp0 = out + 0;
    float* sp1 = out + 1060864;
    float* sp2 = out + 1326080;

    mega_kernel<<<1 + N_PTS / 16, 1024, 0, stream>>>(pts, ew1, eb1, ew2, eb2, feats,
                                                     fi0, fi1, fi2, sp0, sp1, sp2);
    tail_kernel<<<336, 256, 0, stream>>>(feats, fi0, fi1, fi2, mw1, mb1, mw2, mb2, out);
}